// Round 1
// baseline (244.185 us; speedup 1.0000x reference)
//
#include <hip/hip_runtime.h>
#include <math.h>

#ifndef __has_builtin
#define __has_builtin(x) 0
#endif

#define NPTS   131072
#define FCH    16
#define CSND   343.0f
#define PB     32           // points per pass
#define BLOCK  256          // 4 waves
#define GRID   1024         // 4 WG/CU * 256 CUs, persistent (4 passes/block)
#define NBLK   (NPTS / PB)  // 4096

typedef _Float16 half8 __attribute__((ext_vector_type(8)));
typedef _Float16 half2v __attribute__((ext_vector_type(2)));
typedef float    f32x4 __attribute__((ext_vector_type(4)));

static __device__ __forceinline__ unsigned pack2(float a, float b) {
#if __has_builtin(__builtin_amdgcn_cvt_pkrtz)
  return __builtin_bit_cast(unsigned, __builtin_amdgcn_cvt_pkrtz(a, b));
#else
  half2v v; v[0] = (_Float16)a; v[1] = (_Float16)b;
  return __builtin_bit_cast(unsigned, v);
#endif
}

// tanh(x) = 1 - 2/(e^{2x}+1): 5 VALU ops, monotone-correct at +/-inf.
static __device__ __forceinline__ float mytanh(float x) {
#if __has_builtin(__builtin_amdgcn_exp2f)
  float e = __builtin_amdgcn_exp2f(2.885390082f * x);   // 2*log2(e)*x
#else
  float e = __expf(2.0f * x);
#endif
  return fmaf(-2.0f, __builtin_amdgcn_rcpf(e + 1.0f), 1.0f);
}

// PB=32, single 40 KB LDS buffer -> 4 WG/CU (4*40960 = 163840 = full pool):
//   s_A[160][64] dw : A f16, rows R = v*32 + p (v=0..4: h1,d0,d1,d2,c1; p=0..31),
//                     chunk c (4 dw = 8 units) stored at (c ^ (R&15))
//   s_HG ALIASES s_A dwords [0..4096): point p: h2-halves [p*128..+63],
//                     G [p*128+64..+127]. dword q = 32*nh + 16*pr + col holds
//                     pack2(ntl=2pr, 2pr+1), chunk-swizzled (cq ^ (p&15)).
//                     w3f rows permuted to match. Legal because C reads only
//                     registers and all of s_A is dead after B's last ds_read.
// Pass structure (4 barriers, but 4 passes/block vs previous 8 -> same 16
// barrier events per wave as the old 2-barrier/8-pass layout):
//   A(i) wr s_A | b1 | B(i) rd s_A | b2 | C(i) wr HG-alias | b3 |
//   D(i) rd HG  | b4 (protects next A's overwrite)
// Phase B: wave w owns quadrant (ph = w>>1: points 16ph..+15, nh = w&1: cols
//   64nh..+63); STAGED: v=1..3 -> bsum (frees 48 regs), then v=0,4.
// Phase D: all 4 waves: m-tile ph, n-tile nh (re/im); residual in-lane.

__global__ __launch_bounds__(BLOCK, 4) void helmholtz_kernel(
    const float* __restrict__ x,      // [N,3]
    const float* __restrict__ omega,  // [16]
    const float* __restrict__ W1,     // [3,128]
    const float* __restrict__ b1,     // [128]
    const float* __restrict__ W2,     // [128,128]
    const float* __restrict__ b2,     // [128]
    const float* __restrict__ W3,     // [128,32]
    const float* __restrict__ b3,     // [32]
    float* __restrict__ out)
{
  __shared__ unsigned s_A[160 * 64];   // 40 KB; s_HG aliases dwords [0..4096)

  const int tid  = threadIdx.x;
  const int w    = tid >> 6;   // wave 0..3
  const int l    = tid & 63;
  const int col  = l & 15;
  const int quad = l >> 4;
  const int ph   = w >> 1;     // point-half (B and D m-tile)
  const int nh   = w & 1;      // n-half (B); re/im tile (D)

  // ---- phase A task: points pA, pA+16; units 8g..8g+7 ----
  const int pA = tid >> 4;
  const int g  = tid & 15;
  float wx[8], wy[8], wz[8], bB[8];
#pragma unroll
  for (int u = 0; u < 8; u++) {
    int unit = 8 * g + u;
    wx[u] = W1[unit]; wy[u] = W1[128 + unit]; wz[u] = W1[256 + unit];
    bB[u] = b1[unit];
  }

  // ---- W2^T fragments: 4 n-tiles (cols 64*nh + 16*t4 + col), 64 VGPRs ----
  half8 w2f[4][4];
#pragma unroll
  for (int t4 = 0; t4 < 4; t4++) {
    const int n = 64 * nh + 16 * t4 + col;
#pragma unroll
    for (int ks = 0; ks < 4; ks++) {
      half8 f;
#pragma unroll
      for (int j8 = 0; j8 < 8; j8++)
        f[j8] = (_Float16)W2[(ks * 32 + (quad << 3) + j8) * 128 + n];
      w2f[t4][ks] = f;
    }
  }
  // ---- W3^T fragment, j-permuted to match HG layout (16 VGPRs) ----
  half8 w3f[4];
#pragma unroll
  for (int ks = 0; ks < 4; ks++) {
    half8 f;
#pragma unroll
    for (int j8 = 0; j8 < 8; j8++) {
      int kap = ks * 32 + (quad << 3) + j8;
      int q   = kap >> 1;
      int j   = 64 * (q >> 5) + 32 * ((q >> 4) & 1) + 16 * (kap & 1) + (q & 15);
      f[j8] = (_Float16)W3[j * 32 + 16 * nh + col];
    }
    w3f[ks] = f;
  }

  float b2r[4];
#pragma unroll
  for (int t4 = 0; t4 < 4; t4++) b2r[t4] = b2[64 * nh + 16 * t4 + col];
  float k2v = 0.0f;
  if (col >= 1) {
    float om = omega[col] * (1.0f / CSND);
    k2v = om * om;
  }
  const float b3v = b3[16 * nh + col];

  float wsum = 0.0f;
  float xr[2][3];

  auto loadX = [&](int blk) {
    const float* xb = x + (size_t)blk * PB * 3;
#pragma unroll
    for (int hp = 0; hp < 2; hp++) {
      int p = pA + 16 * hp;
      xr[hp][0] = xb[3 * p]; xr[hp][1] = xb[3 * p + 1]; xr[hp][2] = xb[3 * p + 2];
    }
  };

  auto phaseA = [&]() {
    const int cbase = (g ^ pA) << 2;
    float wq[8];
#pragma unroll
    for (int u = 0; u < 8; u++)
      wq[u] = fmaf(wx[u], wx[u], fmaf(wy[u], wy[u], wz[u] * wz[u]));
#pragma unroll
    for (int hp = 0; hp < 2; hp++) {
      int p = pA + 16 * hp;
      float x0 = xr[hp][0], x1 = xr[hp][1], x2 = xr[hp][2];
      float t[8], s[8];
#pragma unroll
      for (int u = 0; u < 8; u++) {
        float z = fmaf(x0, wx[u], fmaf(x1, wy[u], fmaf(x2, wz[u], bB[u])));
        t[u] = mytanh(z);
        s[u] = 1.0f - t[u] * t[u];
      }
      uint4 q;
      q = make_uint4(pack2(t[0], t[1]), pack2(t[2], t[3]),
                     pack2(t[4], t[5]), pack2(t[6], t[7]));
      *(uint4*)&s_A[(p)       * 64 + cbase] = q;
      q = make_uint4(pack2(s[0]*wx[0], s[1]*wx[1]), pack2(s[2]*wx[2], s[3]*wx[3]),
                     pack2(s[4]*wx[4], s[5]*wx[5]), pack2(s[6]*wx[6], s[7]*wx[7]));
      *(uint4*)&s_A[(32 + p)  * 64 + cbase] = q;
      q = make_uint4(pack2(s[0]*wy[0], s[1]*wy[1]), pack2(s[2]*wy[2], s[3]*wy[3]),
                     pack2(s[4]*wy[4], s[5]*wy[5]), pack2(s[6]*wy[6], s[7]*wy[7]));
      *(uint4*)&s_A[(64 + p)  * 64 + cbase] = q;
      q = make_uint4(pack2(s[0]*wz[0], s[1]*wz[1]), pack2(s[2]*wz[2], s[3]*wz[3]),
                     pack2(s[4]*wz[4], s[5]*wz[5]), pack2(s[6]*wz[6], s[7]*wz[7]));
      *(uint4*)&s_A[(96 + p)  * 64 + cbase] = q;
      float c[8];
#pragma unroll
      for (int u = 0; u < 8; u++) c[u] = -2.0f * t[u] * s[u] * wq[u];
      q = make_uint4(pack2(c[0], c[1]), pack2(c[2], c[3]),
                     pack2(c[4], c[5]), pack2(c[6], c[7]));
      *(uint4*)&s_A[(128 + p) * 64 + cbase] = q;
    }
  };

  auto phaseDE = [&]() {
    const int pbase = (16 * ph + col) * 128;   // point row; (row&15)=col swizzle
    f32x4 dy = (f32x4){0.0f, 0.0f, 0.0f, 0.0f};
    f32x4 dl = (f32x4){0.0f, 0.0f, 0.0f, 0.0f};
#pragma unroll
    for (int ks = 0; ks < 4; ks++) {
      int pos = ((((ks << 2) + quad) ^ col) << 2);
      half8 afy = *(const half8*)&s_A[pbase + pos];
      half8 afl = *(const half8*)&s_A[pbase + 64 + pos];
      dy = __builtin_amdgcn_mfma_f32_16x16x32_f16(afy, w3f[ks], dy, 0, 0, 0);
      dl = __builtin_amdgcn_mfma_f32_16x16x32_f16(afl, w3f[ks], dl, 0, 0, 0);
    }
    if (col >= 1) {
#pragma unroll
      for (int r = 0; r < 4; r++) {
        float yv  = dy[r] + b3v;
        float res = fmaf(k2v, yv, dl[r]);
        wsum += res * res;
      }
    }
  };

  // ---- main loop: A | b1 | B | b2 | C | b3 | D | b4 ----
  loadX(blockIdx.x);
  for (int blk = blockIdx.x; blk < NBLK; blk += gridDim.x) {
    phaseA();                       // writes s_A (incl. HG-alias region)
    __syncthreads();                // b1: s_A ready

    int nblk = blk + (int)gridDim.x;
    if (nblk < NBLK) loadX(nblk);   // prefetch x for next pass

    // ---- B(i): quadrant GEMM, STAGED to cap register pressure ----
    f32x4 bsum[4], acch[4], accc[4];
    {
      // stage 1: direction vectors v=1..3 -> accd, collapse to bsum
      f32x4 accd[3][4];
#pragma unroll
      for (int d = 0; d < 3; d++)
#pragma unroll
        for (int t4 = 0; t4 < 4; t4++)
          accd[d][t4] = (f32x4){0.0f, 0.0f, 0.0f, 0.0f};
#pragma unroll
      for (int d = 0; d < 3; d++) {
        const int rb = ((d + 1) * 32 + 16 * ph + col) * 64;
#pragma unroll
        for (int ks = 0; ks < 4; ks++) {
          half8 af = *(const half8*)&s_A[rb + ((((ks << 2) + quad) ^ col) << 2)];
          accd[d][0] = __builtin_amdgcn_mfma_f32_16x16x32_f16(af, w2f[0][ks], accd[d][0], 0, 0, 0);
          accd[d][1] = __builtin_amdgcn_mfma_f32_16x16x32_f16(af, w2f[1][ks], accd[d][1], 0, 0, 0);
          accd[d][2] = __builtin_amdgcn_mfma_f32_16x16x32_f16(af, w2f[2][ks], accd[d][2], 0, 0, 0);
          accd[d][3] = __builtin_amdgcn_mfma_f32_16x16x32_f16(af, w2f[3][ks], accd[d][3], 0, 0, 0);
        }
      }
#pragma unroll
      for (int t4 = 0; t4 < 4; t4++)
        bsum[t4] = accd[0][t4] * accd[0][t4] + accd[1][t4] * accd[1][t4]
                 + accd[2][t4] * accd[2][t4];
    }
    {
      // stage 2: h1 (v=0) and c1 (v=4)
#pragma unroll
      for (int t4 = 0; t4 < 4; t4++) {
        acch[t4] = (f32x4){0.0f, 0.0f, 0.0f, 0.0f};
        accc[t4] = (f32x4){0.0f, 0.0f, 0.0f, 0.0f};
      }
      const int rb0 = (16 * ph + col) * 64;
      const int rb4 = (128 + 16 * ph + col) * 64;
#pragma unroll
      for (int ks = 0; ks < 4; ks++) {
        int pos = ((((ks << 2) + quad) ^ col) << 2);
        half8 afh = *(const half8*)&s_A[rb0 + pos];
        half8 afc = *(const half8*)&s_A[rb4 + pos];
        acch[0] = __builtin_amdgcn_mfma_f32_16x16x32_f16(afh, w2f[0][ks], acch[0], 0, 0, 0);
        acch[1] = __builtin_amdgcn_mfma_f32_16x16x32_f16(afh, w2f[1][ks], acch[1], 0, 0, 0);
        acch[2] = __builtin_amdgcn_mfma_f32_16x16x32_f16(afh, w2f[2][ks], acch[2], 0, 0, 0);
        acch[3] = __builtin_amdgcn_mfma_f32_16x16x32_f16(afh, w2f[3][ks], acch[3], 0, 0, 0);
        accc[0] = __builtin_amdgcn_mfma_f32_16x16x32_f16(afc, w2f[0][ks], accc[0], 0, 0, 0);
        accc[1] = __builtin_amdgcn_mfma_f32_16x16x32_f16(afc, w2f[1][ks], accc[1], 0, 0, 0);
        accc[2] = __builtin_amdgcn_mfma_f32_16x16x32_f16(afc, w2f[2][ks], accc[2], 0, 0, 0);
        accc[3] = __builtin_amdgcn_mfma_f32_16x16x32_f16(afc, w2f[3][ks], accc[3], 0, 0, 0);
      }
    }
    __syncthreads();                // b2: all waves' B reads of s_A complete

    // ---- C(i): layer-2 elementwise; paired-dword writes into HG alias ----
#pragma unroll
    for (int r = 0; r < 4; r++) {
      int p = 16 * ph + (quad << 2) + r;
      float t2[4], gg[4];
#pragma unroll
      for (int t4 = 0; t4 < 4; t4++) {
        float z2 = acch[t4][r] + b2r[t4];
        float t  = mytanh(z2);
        float s2 = 1.0f - t * t;
        t2[t4] = t;
        gg[t4] = s2 * (accc[t4][r] - 2.0f * t * bsum[t4][r]);
      }
      int pb = p * 128;
#pragma unroll
      for (int pr = 0; pr < 2; pr++) {
        int q   = 32 * nh + 16 * pr + col;
        int pos = (((q >> 2) ^ (p & 15)) << 2) + (q & 3);
        s_A[pb + pos]      = pack2(t2[2 * pr], t2[2 * pr + 1]);
        s_A[pb + 64 + pos] = pack2(gg[2 * pr], gg[2 * pr + 1]);
      }
    }
    __syncthreads();                // b3: HG ready for D

    phaseDE();                      // D(i): reads HG alias
    __syncthreads();                // b4: D reads done before next A's writes
  }

  // ---- final: wave reduce, one atomic per wave ----
#pragma unroll
  for (int off = 32; off > 0; off >>= 1)
    wsum += __shfl_down(wsum, off, 64);
  if (l == 0)
    atomicAdd(out, wsum * (1.0f / ((float)NPTS * (float)(FCH - 1))));
}

extern "C" void kernel_launch(void* const* d_in, const int* in_sizes, int n_in,
                              void* d_out, int out_size, void* d_ws, size_t ws_size,
                              hipStream_t stream) {
  const float* x     = (const float*)d_in[0];
  const float* omega = (const float*)d_in[1];
  const float* W1    = (const float*)d_in[2];
  const float* b1    = (const float*)d_in[3];
  const float* W2    = (const float*)d_in[4];
  const float* b2    = (const float*)d_in[5];
  const float* W3    = (const float*)d_in[6];
  const float* b3    = (const float*)d_in[7];
  float* out = (float*)d_out;

  (void)hipMemsetAsync(out, 0, sizeof(float), stream);
  helmholtz_kernel<<<GRID, BLOCK, 0, stream>>>(x, omega, W1, b1, W2, b2, W3, b3, out);
}

// Round 2
// 148.895 us; speedup vs baseline: 1.6400x; 1.6400x over previous
//
#include <hip/hip_runtime.h>
#include <math.h>

#ifndef __has_builtin
#define __has_builtin(x) 0
#endif

#define NPTS   131072
#define FCH    16
#define CSND   343.0f
#define PB     32           // points per pass
#define BLOCK  256          // 4 waves
#define GRID   1024         // 4 WG/CU * 256 CUs, persistent (4 passes/block)
#define NBLK   (NPTS / PB)  // 4096

typedef _Float16 half8 __attribute__((ext_vector_type(8)));
typedef _Float16 half2v __attribute__((ext_vector_type(2)));
typedef float    f32x4 __attribute__((ext_vector_type(4)));

static __device__ __forceinline__ unsigned pack2(float a, float b) {
#if __has_builtin(__builtin_amdgcn_cvt_pkrtz)
  return __builtin_bit_cast(unsigned, __builtin_amdgcn_cvt_pkrtz(a, b));
#else
  half2v v; v[0] = (_Float16)a; v[1] = (_Float16)b;
  return __builtin_bit_cast(unsigned, v);
#endif
}

// tanh(x) = 1 - 2/(e^{2x}+1): 5 VALU ops, monotone-correct at +/-inf.
static __device__ __forceinline__ float mytanh(float x) {
#if __has_builtin(__builtin_amdgcn_exp2f)
  float e = __builtin_amdgcn_exp2f(2.885390082f * x);   // 2*log2(e)*x
#else
  float e = __expf(2.0f * x);
#endif
  return fmaf(-2.0f, __builtin_amdgcn_rcpf(e + 1.0f), 1.0f);
}

// Single 40 KB LDS buffer -> 4 WG/CU (4*40960 = 163840 = full pool).
//   s_A[160][64] dw : A f16, rows R = v*32 + p (v=0..4: h1,d0,d1,d2,c1),
//                     chunk c (4 dw = 8 units) stored at (c ^ (R&15)).
//   s_HG ALIASES s_A dwords [0..4096): point p block p*128: h2 [0..63],
//                     G [64..127]. Dword q (=16*w_src+col_src) holds true cols
//                     (32*(q>>4)+(q&15), +16) packed; chunk-swizzled by (p&15).
//                     w3f rows permuted to match (j = 32ks+16(j8&1)+4quad+(j8>>1)).
// Pass: A | b1 | B | b2 | C | b3 | [loadW1] D | b4.
// Register budget (target 128 total, 4 waves/SIMD):
//   - w2f halved to [2][4] (32 regs): wave owns n-quarter (32 cols), loops both
//     m-tiles (A-frags read twice; LDS pipe has headroom).
//   - stage-1 collapses per-d: accd[2][2] (16) -> bsum, not accd[3][4] (48).
//   - W1/b1 (32 regs) reloaded per pass before D (L1-hot, latency hidden under
//     D's MFMAs); opaque zoff defeats LICM so live range is only D->A.

__global__ __launch_bounds__(BLOCK, 4) void helmholtz_kernel(
    const float* __restrict__ x,      // [N,3]
    const float* __restrict__ omega,  // [16]
    const float* __restrict__ W1,     // [3,128]
    const float* __restrict__ b1,     // [128]
    const float* __restrict__ W2,     // [128,128]
    const float* __restrict__ b2,     // [128]
    const float* __restrict__ W3,     // [128,32]
    const float* __restrict__ b3,     // [32]
    float* __restrict__ out)
{
  __shared__ unsigned s_A[160 * 64];   // 40 KB; s_HG aliases dwords [0..4096)

  const int tid  = threadIdx.x;
  const int w    = tid >> 6;   // wave 0..3
  const int l    = tid & 63;
  const int col  = l & 15;
  const int quad = l >> 4;
  const int ph   = w >> 1;     // D m-tile
  const int nh   = w & 1;      // D re/im tile

  // ---- phase A task: points pA, pA+16; units 8g..8g+7 ----
  const int pA = tid >> 4;
  const int g  = tid & 15;

  // ---- W2^T fragments: 2 n-tiles (cols 32*w + 16*t4 + col), 32 VGPRs ----
  half8 w2f[2][4];
#pragma unroll
  for (int t4 = 0; t4 < 2; t4++) {
    const int n = 32 * w + 16 * t4 + col;
#pragma unroll
    for (int ks = 0; ks < 4; ks++) {
      half8 f;
#pragma unroll
      for (int j8 = 0; j8 < 8; j8++)
        f[j8] = (_Float16)W2[(ks * 32 + (quad << 3) + j8) * 128 + n];
      w2f[t4][ks] = f;
    }
  }
  // ---- W3^T fragment, permuted to HG layout (16 VGPRs) ----
  half8 w3f[4];
#pragma unroll
  for (int ks = 0; ks < 4; ks++) {
    half8 f;
#pragma unroll
    for (int j8 = 0; j8 < 8; j8++) {
      int j = 32 * ks + 16 * (j8 & 1) + 4 * quad + (j8 >> 1);
      f[j8] = (_Float16)W3[j * 32 + 16 * nh + col];
    }
    w3f[ks] = f;
  }

  float b2r[2];
#pragma unroll
  for (int t4 = 0; t4 < 2; t4++) b2r[t4] = b2[32 * w + 16 * t4 + col];
  float k2v = 0.0f;
  if (col >= 1) {
    float om = omega[col] * (1.0f / CSND);
    k2v = om * om;
  }
  const float b3v = b3[16 * nh + col];

  float wsum = 0.0f;
  float xr[2][3];
  float wx[8], wy[8], wz[8], bB[8];

  auto loadW1 = [&](int zo) {
#pragma unroll
    for (int u = 0; u < 8; u++) {
      int unit = 8 * g + u + zo;
      wx[u] = W1[unit]; wy[u] = W1[128 + unit]; wz[u] = W1[256 + unit];
      bB[u] = b1[unit];
    }
  };

  auto loadX = [&](int blk) {
    const float* xb = x + (size_t)blk * PB * 3;
#pragma unroll
    for (int hp = 0; hp < 2; hp++) {
      int p = pA + 16 * hp;
      xr[hp][0] = xb[3 * p]; xr[hp][1] = xb[3 * p + 1]; xr[hp][2] = xb[3 * p + 2];
    }
  };

  auto phaseA = [&]() {
    const int cbase = (g ^ pA) << 2;
    float wq[8];
#pragma unroll
    for (int u = 0; u < 8; u++)
      wq[u] = fmaf(wx[u], wx[u], fmaf(wy[u], wy[u], wz[u] * wz[u]));
#pragma unroll
    for (int hp = 0; hp < 2; hp++) {
      int p = pA + 16 * hp;
      float x0 = xr[hp][0], x1 = xr[hp][1], x2 = xr[hp][2];
      float t[8], s[8];
#pragma unroll
      for (int u = 0; u < 8; u++) {
        float z = fmaf(x0, wx[u], fmaf(x1, wy[u], fmaf(x2, wz[u], bB[u])));
        t[u] = mytanh(z);
        s[u] = 1.0f - t[u] * t[u];
      }
      uint4 q;
      q = make_uint4(pack2(t[0], t[1]), pack2(t[2], t[3]),
                     pack2(t[4], t[5]), pack2(t[6], t[7]));
      *(uint4*)&s_A[(p)       * 64 + cbase] = q;
      q = make_uint4(pack2(s[0]*wx[0], s[1]*wx[1]), pack2(s[2]*wx[2], s[3]*wx[3]),
                     pack2(s[4]*wx[4], s[5]*wx[5]), pack2(s[6]*wx[6], s[7]*wx[7]));
      *(uint4*)&s_A[(32 + p)  * 64 + cbase] = q;
      q = make_uint4(pack2(s[0]*wy[0], s[1]*wy[1]), pack2(s[2]*wy[2], s[3]*wy[3]),
                     pack2(s[4]*wy[4], s[5]*wy[5]), pack2(s[6]*wy[6], s[7]*wy[7]));
      *(uint4*)&s_A[(64 + p)  * 64 + cbase] = q;
      q = make_uint4(pack2(s[0]*wz[0], s[1]*wz[1]), pack2(s[2]*wz[2], s[3]*wz[3]),
                     pack2(s[4]*wz[4], s[5]*wz[5]), pack2(s[6]*wz[6], s[7]*wz[7]));
      *(uint4*)&s_A[(96 + p)  * 64 + cbase] = q;
      float c[8];
#pragma unroll
      for (int u = 0; u < 8; u++) c[u] = -2.0f * t[u] * s[u] * wq[u];
      q = make_uint4(pack2(c[0], c[1]), pack2(c[2], c[3]),
                     pack2(c[4], c[5]), pack2(c[6], c[7]));
      *(uint4*)&s_A[(128 + p) * 64 + cbase] = q;
    }
  };

  auto phaseDE = [&]() {
    const int pbase = (16 * ph + col) * 128;   // point row; (row&15)=col swizzle
    f32x4 dy = (f32x4){0.0f, 0.0f, 0.0f, 0.0f};
    f32x4 dl = (f32x4){0.0f, 0.0f, 0.0f, 0.0f};
#pragma unroll
    for (int ks = 0; ks < 4; ks++) {
      int pos = ((((ks << 2) + quad) ^ col) << 2);
      half8 afy = *(const half8*)&s_A[pbase + pos];
      half8 afl = *(const half8*)&s_A[pbase + 64 + pos];
      dy = __builtin_amdgcn_mfma_f32_16x16x32_f16(afy, w3f[ks], dy, 0, 0, 0);
      dl = __builtin_amdgcn_mfma_f32_16x16x32_f16(afl, w3f[ks], dl, 0, 0, 0);
    }
    if (col >= 1) {
#pragma unroll
      for (int r = 0; r < 4; r++) {
        float yv  = dy[r] + b3v;
        float res = fmaf(k2v, yv, dl[r]);
        wsum += res * res;
      }
    }
  };

  // ---- main loop: A | b1 | B | b2 | C | b3 | [loadW1] D | b4 ----
  loadW1(0);
  loadX(blockIdx.x);
  int zoff = 0;
  for (int blk = blockIdx.x; blk < NBLK; blk += gridDim.x) {
    phaseA();                       // writes s_A (incl. HG-alias region)
    __syncthreads();                // b1: s_A ready

    int nblk = blk + (int)gridDim.x;
    if (nblk < NBLK) loadX(nblk);   // prefetch x for next pass

    // ---- B(i): n-quarter x both m-tiles; per-d collapse caps registers ----
    f32x4 bsum[2][2], acch[2][2], accc[2][2];
#pragma unroll
    for (int mt = 0; mt < 2; mt++)
#pragma unroll
      for (int t4 = 0; t4 < 2; t4++)
        bsum[mt][t4] = (f32x4){0.0f, 0.0f, 0.0f, 0.0f};
#pragma unroll
    for (int d = 0; d < 3; d++) {
      f32x4 accd[2][2];
#pragma unroll
      for (int mt = 0; mt < 2; mt++)
#pragma unroll
        for (int t4 = 0; t4 < 2; t4++)
          accd[mt][t4] = (f32x4){0.0f, 0.0f, 0.0f, 0.0f};
#pragma unroll
      for (int mt = 0; mt < 2; mt++) {
        const int rb = ((d + 1) * 32 + 16 * mt + col) * 64;
#pragma unroll
        for (int ks = 0; ks < 4; ks++) {
          half8 af = *(const half8*)&s_A[rb + ((((ks << 2) + quad) ^ col) << 2)];
          accd[mt][0] = __builtin_amdgcn_mfma_f32_16x16x32_f16(af, w2f[0][ks], accd[mt][0], 0, 0, 0);
          accd[mt][1] = __builtin_amdgcn_mfma_f32_16x16x32_f16(af, w2f[1][ks], accd[mt][1], 0, 0, 0);
        }
      }
#pragma unroll
      for (int mt = 0; mt < 2; mt++)
#pragma unroll
        for (int t4 = 0; t4 < 2; t4++)
          bsum[mt][t4] += accd[mt][t4] * accd[mt][t4];
    }
#pragma unroll
    for (int mt = 0; mt < 2; mt++)
#pragma unroll
      for (int t4 = 0; t4 < 2; t4++) {
        acch[mt][t4] = (f32x4){0.0f, 0.0f, 0.0f, 0.0f};
        accc[mt][t4] = (f32x4){0.0f, 0.0f, 0.0f, 0.0f};
      }
#pragma unroll
    for (int mt = 0; mt < 2; mt++) {
      const int rb0 = (16 * mt + col) * 64;
      const int rb4 = (128 + 16 * mt + col) * 64;
#pragma unroll
      for (int ks = 0; ks < 4; ks++) {
        int pos = ((((ks << 2) + quad) ^ col) << 2);
        half8 afh = *(const half8*)&s_A[rb0 + pos];
        half8 afc = *(const half8*)&s_A[rb4 + pos];
        acch[mt][0] = __builtin_amdgcn_mfma_f32_16x16x32_f16(afh, w2f[0][ks], acch[mt][0], 0, 0, 0);
        acch[mt][1] = __builtin_amdgcn_mfma_f32_16x16x32_f16(afh, w2f[1][ks], acch[mt][1], 0, 0, 0);
        accc[mt][0] = __builtin_amdgcn_mfma_f32_16x16x32_f16(afc, w2f[0][ks], accc[mt][0], 0, 0, 0);
        accc[mt][1] = __builtin_amdgcn_mfma_f32_16x16x32_f16(afc, w2f[1][ks], accc[mt][1], 0, 0, 0);
      }
    }
    __syncthreads();                // b2: all waves' B reads of s_A complete

    // ---- C(i): layer-2 elementwise; packed (t4=0,t4=1) writes into HG ----
    {
      const int q = 16 * w + col;   // dword index within 64-dword half-block
#pragma unroll
      for (int mt = 0; mt < 2; mt++)
#pragma unroll
        for (int r = 0; r < 4; r++) {
          int p = 16 * mt + (quad << 2) + r;
          float t2[2], gg[2];
#pragma unroll
          for (int t4 = 0; t4 < 2; t4++) {
            float z2 = acch[mt][t4][r] + b2r[t4];
            float t  = mytanh(z2);
            float s2 = 1.0f - t * t;
            t2[t4] = t;
            gg[t4] = s2 * (accc[mt][t4][r] - 2.0f * t * bsum[mt][t4][r]);
          }
          int pos = (((q >> 2) ^ (p & 15)) << 2) + (q & 3);
          int pb  = p * 128;
          s_A[pb + pos]      = pack2(t2[0], t2[1]);
          s_A[pb + 64 + pos] = pack2(gg[0], gg[1]);
        }
    }
    __syncthreads();                // b3: HG ready for D

    asm volatile("" : "+v"(zoff));  // opaque 0: forces per-pass W1 reload
    loadW1(zoff);                   // refresh wx/wy/wz/bB; hides under D
    phaseDE();                      // D(i): reads HG alias
    __syncthreads();                // b4: D reads done before next A's writes
  }

  // ---- final: wave reduce, one atomic per wave ----
#pragma unroll
  for (int off = 32; off > 0; off >>= 1)
    wsum += __shfl_down(wsum, off, 64);
  if (l == 0)
    atomicAdd(out, wsum * (1.0f / ((float)NPTS * (float)(FCH - 1))));
}

extern "C" void kernel_launch(void* const* d_in, const int* in_sizes, int n_in,
                              void* d_out, int out_size, void* d_ws, size_t ws_size,
                              hipStream_t stream) {
  const float* x     = (const float*)d_in[0];
  const float* omega = (const float*)d_in[1];
  const float* W1    = (const float*)d_in[2];
  const float* b1    = (const float*)d_in[3];
  const float* W2    = (const float*)d_in[4];
  const float* b2    = (const float*)d_in[5];
  const float* W3    = (const float*)d_in[6];
  const float* b3    = (const float*)d_in[7];
  float* out = (float*)d_out;

  (void)hipMemsetAsync(out, 0, sizeof(float), stream);
  helmholtz_kernel<<<GRID, BLOCK, 0, stream>>>(x, omega, W1, b1, W2, b2, W3, b3, out);
}

// Round 3
// 140.783 us; speedup vs baseline: 1.7345x; 1.0576x over previous
//
#include <hip/hip_runtime.h>
#include <math.h>

#ifndef __has_builtin
#define __has_builtin(x) 0
#endif

#define NPTS   131072
#define FCH    16
#define CSND   343.0f
#define PB     32           // points per pass
#define BLOCK  256          // 4 waves
#define GRID   768          // 3 WG/CU * 256 CUs, persistent (5-6 passes/block)
#define NBLK   (NPTS / PB)  // 4096

typedef _Float16 half8 __attribute__((ext_vector_type(8)));
typedef _Float16 half2v __attribute__((ext_vector_type(2)));
typedef float    f32x4 __attribute__((ext_vector_type(4)));

static __device__ __forceinline__ unsigned pack2(float a, float b) {
#if __has_builtin(__builtin_amdgcn_cvt_pkrtz)
  return __builtin_bit_cast(unsigned, __builtin_amdgcn_cvt_pkrtz(a, b));
#else
  half2v v; v[0] = (_Float16)a; v[1] = (_Float16)b;
  return __builtin_bit_cast(unsigned, v);
#endif
}

// tanh(x) = 1 - 2/(e^{2x}+1): 5 VALU ops, monotone-correct at +/-inf.
static __device__ __forceinline__ float mytanh(float x) {
#if __has_builtin(__builtin_amdgcn_exp2f)
  float e = __builtin_amdgcn_exp2f(2.885390082f * x);   // 2*log2(e)*x
#else
  float e = __expf(2.0f * x);
#endif
  return fmaf(-2.0f, __builtin_amdgcn_rcpf(e + 1.0f), 1.0f);
}

// Single 40 KB LDS buffer; __launch_bounds__(256,3) -> 3 WG/CU (120 KB LDS,
// ~168 unified regs/thread -> true demand ~160 fits with ZERO spills; the
// 4-WG/128-reg attempt spilled 20-30 MB of scratch traffic, net loss).
//   s_A[160][64] dw : A f16, rows R = v*32 + p (v=0..4: h1,d0,d1,d2,c1),
//                     chunk c (4 dw = 8 units) stored at (c ^ (R&15)).
//   s_HG ALIASES s_A dwords [0..4096): point p block p*128: h2 [0..63],
//                     G [64..127]. Dword q (=16*w_src+col_src) holds true cols
//                     (32*(q>>4)+(q&15), +16) packed; chunk-swizzled by (p&15).
//                     w3f rows permuted to match (j = 32ks+16(j8&1)+4quad+(j8>>1)).
//                     Aliasing is legal: C reads only registers, and all of
//                     s_A is dead after B's last ds_read (barrier b2).
// Pass: A | b1 | B | b2 | C | b3 | D | b4. Cross-WG overlap (3 WGs at
// different phases per CU) hides barrier stalls.
// Phase B: wave owns n-quarter (32 cols = 32*w..+31), loops both m-tiles;
//   stage-1 collapses per-direction (accd[2][2] -> bsum) to cap registers.

__global__ __launch_bounds__(BLOCK, 3) void helmholtz_kernel(
    const float* __restrict__ x,      // [N,3]
    const float* __restrict__ omega,  // [16]
    const float* __restrict__ W1,     // [3,128]
    const float* __restrict__ b1,     // [128]
    const float* __restrict__ W2,     // [128,128]
    const float* __restrict__ b2,     // [128]
    const float* __restrict__ W3,     // [128,32]
    const float* __restrict__ b3,     // [32]
    float* __restrict__ out)
{
  __shared__ unsigned s_A[160 * 64];   // 40 KB; s_HG aliases dwords [0..4096)

  const int tid  = threadIdx.x;
  const int w    = tid >> 6;   // wave 0..3
  const int l    = tid & 63;
  const int col  = l & 15;
  const int quad = l >> 4;
  const int ph   = w >> 1;     // D m-tile
  const int nh   = w & 1;      // D re/im tile

  // ---- phase A task: points pA, pA+16; units 8g..8g+7 ----
  const int pA = tid >> 4;
  const int g  = tid & 15;
  float wx[8], wy[8], wz[8], bB[8];
#pragma unroll
  for (int u = 0; u < 8; u++) {
    int unit = 8 * g + u;
    wx[u] = W1[unit]; wy[u] = W1[128 + unit]; wz[u] = W1[256 + unit];
    bB[u] = b1[unit];
  }

  // ---- W2^T fragments: 2 n-tiles (cols 32*w + 16*t4 + col), 32 VGPRs ----
  half8 w2f[2][4];
#pragma unroll
  for (int t4 = 0; t4 < 2; t4++) {
    const int n = 32 * w + 16 * t4 + col;
#pragma unroll
    for (int ks = 0; ks < 4; ks++) {
      half8 f;
#pragma unroll
      for (int j8 = 0; j8 < 8; j8++)
        f[j8] = (_Float16)W2[(ks * 32 + (quad << 3) + j8) * 128 + n];
      w2f[t4][ks] = f;
    }
  }
  // ---- W3^T fragment, permuted to HG layout (16 VGPRs) ----
  half8 w3f[4];
#pragma unroll
  for (int ks = 0; ks < 4; ks++) {
    half8 f;
#pragma unroll
    for (int j8 = 0; j8 < 8; j8++) {
      int j = 32 * ks + 16 * (j8 & 1) + 4 * quad + (j8 >> 1);
      f[j8] = (_Float16)W3[j * 32 + 16 * nh + col];
    }
    w3f[ks] = f;
  }

  float b2r[2];
#pragma unroll
  for (int t4 = 0; t4 < 2; t4++) b2r[t4] = b2[32 * w + 16 * t4 + col];
  float k2v = 0.0f;
  if (col >= 1) {
    float om = omega[col] * (1.0f / CSND);
    k2v = om * om;
  }
  const float b3v = b3[16 * nh + col];

  float wsum = 0.0f;
  float xr[2][3];

  auto loadX = [&](int blk) {
    const float* xb = x + (size_t)blk * PB * 3;
#pragma unroll
    for (int hp = 0; hp < 2; hp++) {
      int p = pA + 16 * hp;
      xr[hp][0] = xb[3 * p]; xr[hp][1] = xb[3 * p + 1]; xr[hp][2] = xb[3 * p + 2];
    }
  };

  auto phaseA = [&]() {
    const int cbase = (g ^ pA) << 2;
    float wq[8];
#pragma unroll
    for (int u = 0; u < 8; u++)
      wq[u] = fmaf(wx[u], wx[u], fmaf(wy[u], wy[u], wz[u] * wz[u]));
#pragma unroll
    for (int hp = 0; hp < 2; hp++) {
      int p = pA + 16 * hp;
      float x0 = xr[hp][0], x1 = xr[hp][1], x2 = xr[hp][2];
      float t[8], s[8];
#pragma unroll
      for (int u = 0; u < 8; u++) {
        float z = fmaf(x0, wx[u], fmaf(x1, wy[u], fmaf(x2, wz[u], bB[u])));
        t[u] = mytanh(z);
        s[u] = 1.0f - t[u] * t[u];
      }
      uint4 q;
      q = make_uint4(pack2(t[0], t[1]), pack2(t[2], t[3]),
                     pack2(t[4], t[5]), pack2(t[6], t[7]));
      *(uint4*)&s_A[(p)       * 64 + cbase] = q;
      q = make_uint4(pack2(s[0]*wx[0], s[1]*wx[1]), pack2(s[2]*wx[2], s[3]*wx[3]),
                     pack2(s[4]*wx[4], s[5]*wx[5]), pack2(s[6]*wx[6], s[7]*wx[7]));
      *(uint4*)&s_A[(32 + p)  * 64 + cbase] = q;
      q = make_uint4(pack2(s[0]*wy[0], s[1]*wy[1]), pack2(s[2]*wy[2], s[3]*wy[3]),
                     pack2(s[4]*wy[4], s[5]*wy[5]), pack2(s[6]*wy[6], s[7]*wy[7]));
      *(uint4*)&s_A[(64 + p)  * 64 + cbase] = q;
      q = make_uint4(pack2(s[0]*wz[0], s[1]*wz[1]), pack2(s[2]*wz[2], s[3]*wz[3]),
                     pack2(s[4]*wz[4], s[5]*wz[5]), pack2(s[6]*wz[6], s[7]*wz[7]));
      *(uint4*)&s_A[(96 + p)  * 64 + cbase] = q;
      float c[8];
#pragma unroll
      for (int u = 0; u < 8; u++) c[u] = -2.0f * t[u] * s[u] * wq[u];
      q = make_uint4(pack2(c[0], c[1]), pack2(c[2], c[3]),
                     pack2(c[4], c[5]), pack2(c[6], c[7]));
      *(uint4*)&s_A[(128 + p) * 64 + cbase] = q;
    }
  };

  auto phaseDE = [&]() {
    const int pbase = (16 * ph + col) * 128;   // point row; (row&15)=col swizzle
    f32x4 dy = (f32x4){0.0f, 0.0f, 0.0f, 0.0f};
    f32x4 dl = (f32x4){0.0f, 0.0f, 0.0f, 0.0f};
#pragma unroll
    for (int ks = 0; ks < 4; ks++) {
      int pos = ((((ks << 2) + quad) ^ col) << 2);
      half8 afy = *(const half8*)&s_A[pbase + pos];
      half8 afl = *(const half8*)&s_A[pbase + 64 + pos];
      dy = __builtin_amdgcn_mfma_f32_16x16x32_f16(afy, w3f[ks], dy, 0, 0, 0);
      dl = __builtin_amdgcn_mfma_f32_16x16x32_f16(afl, w3f[ks], dl, 0, 0, 0);
    }
    if (col >= 1) {
#pragma unroll
      for (int r = 0; r < 4; r++) {
        float yv  = dy[r] + b3v;
        float res = fmaf(k2v, yv, dl[r]);
        wsum += res * res;
      }
    }
  };

  // ---- main loop: A | b1 | B | b2 | C | b3 | D | b4 ----
  loadX(blockIdx.x);
  for (int blk = blockIdx.x; blk < NBLK; blk += gridDim.x) {
    phaseA();                       // writes s_A (incl. HG-alias region)
    __syncthreads();                // b1: s_A ready

    int nblk = blk + (int)gridDim.x;
    if (nblk < NBLK) loadX(nblk);   // prefetch x for next pass

    // ---- B(i): n-quarter x both m-tiles; per-d collapse caps registers ----
    f32x4 bsum[2][2], acch[2][2], accc[2][2];
#pragma unroll
    for (int mt = 0; mt < 2; mt++)
#pragma unroll
      for (int t4 = 0; t4 < 2; t4++)
        bsum[mt][t4] = (f32x4){0.0f, 0.0f, 0.0f, 0.0f};
#pragma unroll
    for (int d = 0; d < 3; d++) {
      f32x4 accd[2][2];
#pragma unroll
      for (int mt = 0; mt < 2; mt++)
#pragma unroll
        for (int t4 = 0; t4 < 2; t4++)
          accd[mt][t4] = (f32x4){0.0f, 0.0f, 0.0f, 0.0f};
#pragma unroll
      for (int mt = 0; mt < 2; mt++) {
        const int rb = ((d + 1) * 32 + 16 * mt + col) * 64;
#pragma unroll
        for (int ks = 0; ks < 4; ks++) {
          half8 af = *(const half8*)&s_A[rb + ((((ks << 2) + quad) ^ col) << 2)];
          accd[mt][0] = __builtin_amdgcn_mfma_f32_16x16x32_f16(af, w2f[0][ks], accd[mt][0], 0, 0, 0);
          accd[mt][1] = __builtin_amdgcn_mfma_f32_16x16x32_f16(af, w2f[1][ks], accd[mt][1], 0, 0, 0);
        }
      }
#pragma unroll
      for (int mt = 0; mt < 2; mt++)
#pragma unroll
        for (int t4 = 0; t4 < 2; t4++)
          bsum[mt][t4] += accd[mt][t4] * accd[mt][t4];
    }
#pragma unroll
    for (int mt = 0; mt < 2; mt++)
#pragma unroll
      for (int t4 = 0; t4 < 2; t4++) {
        acch[mt][t4] = (f32x4){0.0f, 0.0f, 0.0f, 0.0f};
        accc[mt][t4] = (f32x4){0.0f, 0.0f, 0.0f, 0.0f};
      }
#pragma unroll
    for (int mt = 0; mt < 2; mt++) {
      const int rb0 = (16 * mt + col) * 64;
      const int rb4 = (128 + 16 * mt + col) * 64;
#pragma unroll
      for (int ks = 0; ks < 4; ks++) {
        int pos = ((((ks << 2) + quad) ^ col) << 2);
        half8 afh = *(const half8*)&s_A[rb0 + pos];
        half8 afc = *(const half8*)&s_A[rb4 + pos];
        acch[mt][0] = __builtin_amdgcn_mfma_f32_16x16x32_f16(afh, w2f[0][ks], acch[mt][0], 0, 0, 0);
        acch[mt][1] = __builtin_amdgcn_mfma_f32_16x16x32_f16(afh, w2f[1][ks], acch[mt][1], 0, 0, 0);
        accc[mt][0] = __builtin_amdgcn_mfma_f32_16x16x32_f16(afc, w2f[0][ks], accc[mt][0], 0, 0, 0);
        accc[mt][1] = __builtin_amdgcn_mfma_f32_16x16x32_f16(afc, w2f[1][ks], accc[mt][1], 0, 0, 0);
      }
    }
    __syncthreads();                // b2: all waves' B reads of s_A complete

    // ---- C(i): layer-2 elementwise; packed (t4=0,t4=1) writes into HG ----
    {
      const int q = 16 * w + col;   // dword index within 64-dword half-block
#pragma unroll
      for (int mt = 0; mt < 2; mt++)
#pragma unroll
        for (int r = 0; r < 4; r++) {
          int p = 16 * mt + (quad << 2) + r;
          float t2[2], gg[2];
#pragma unroll
          for (int t4 = 0; t4 < 2; t4++) {
            float z2 = acch[mt][t4][r] + b2r[t4];
            float t  = mytanh(z2);
            float s2 = 1.0f - t * t;
            t2[t4] = t;
            gg[t4] = s2 * (accc[mt][t4][r] - 2.0f * t * bsum[mt][t4][r]);
          }
          int pos = (((q >> 2) ^ (p & 15)) << 2) + (q & 3);
          int pb  = p * 128;
          s_A[pb + pos]      = pack2(t2[0], t2[1]);
          s_A[pb + 64 + pos] = pack2(gg[0], gg[1]);
        }
    }
    __syncthreads();                // b3: HG ready for D

    phaseDE();                      // D(i): reads HG alias
    __syncthreads();                // b4: D reads done before next A's writes
  }

  // ---- final: wave reduce, one atomic per wave ----
#pragma unroll
  for (int off = 32; off > 0; off >>= 1)
    wsum += __shfl_down(wsum, off, 64);
  if (l == 0)
    atomicAdd(out, wsum * (1.0f / ((float)NPTS * (float)(FCH - 1))));
}

extern "C" void kernel_launch(void* const* d_in, const int* in_sizes, int n_in,
                              void* d_out, int out_size, void* d_ws, size_t ws_size,
                              hipStream_t stream) {
  const float* x     = (const float*)d_in[0];
  const float* omega = (const float*)d_in[1];
  const float* W1    = (const float*)d_in[2];
  const float* b1    = (const float*)d_in[3];
  const float* W2    = (const float*)d_in[4];
  const float* b2    = (const float*)d_in[5];
  const float* W3    = (const float*)d_in[6];
  const float* b3    = (const float*)d_in[7];
  float* out = (float*)d_out;

  (void)hipMemsetAsync(out, 0, sizeof(float), stream);
  helmholtz_kernel<<<GRID, BLOCK, 0, stream>>>(x, omega, W1, b1, W2, b2, W3, b3, out);
}